// Round 3
// baseline (311.996 us; speedup 1.0000x reference)
//
#include <hip/hip_runtime.h>
#include <math.h>

// Problem constants (from reference): B=256, N=512, M=1024
#define BB 256
#define NN 512
#define MM 1024
#define TOTAL (BB * MM)      // 262144 claims
#define NBLK 256             // main-kernel blocks
#define NTHREADS (NBLK * 256) // 65536 threads, 4 claims/thread
#define KPT 4                // claims per thread
#define EPS_P 1e-7f

// ws layout: float part_sum[NBLK]; float part_cnt[NBLK]
// (fully overwritten every call — no init needed)

__global__ __launch_bounds__(256)
void claim_loss_main(const float* __restrict__ adj,
                     const int*   __restrict__ var_a,
                     const int*   __restrict__ var_b,
                     const int*   __restrict__ rel,
                     const int*   __restrict__ is_true,
                     const unsigned int* __restrict__ mask_raw,
                     float* __restrict__ part_sum,
                     float* __restrict__ part_cnt) {
    // --- inline mask-storage detection (1 broadcast L2-hit load/thread) ----
    // int32 0/1 storage -> upper 3 bytes of every word zero; byte-bool
    // storage -> some upper byte nonzero w.p. 1 - 8^-64.
    const unsigned int w = mask_raw[threadIdx.x & 63];
    const bool bytes_mode = (__ballot((w & 0xFFFFFF00u) != 0u) != 0ull);

    const int tid = blockIdx.x * 256 + threadIdx.x;

    float loss  = 0.0f;
    float valid = 0.0f;

    #pragma unroll
    for (int k = 0; k < KPT; ++k) {
        const int j = tid + k * NTHREADS;   // coalesced across the grid
        const int m = bytes_mode ? (int)((const unsigned char*)mask_raw)[j]
                                 : ((const int*)mask_raw)[j];
        if (m == 0) {                       // True = padding; valid when 0
            const int b = j >> 10;          // M = 1024
            const int a = var_a[j];
            const int c = var_b[j];
            const int r = rel[j];
            const int t = is_true[j];
            float p = adj[((size_t)b << 18) + (a << 9) + c];  // N=512
            // 0=CAUSES,1=FORBIDS,2=ANCESTOR,3=NON_ANCESTOR, >=4 -> 0.5
            float prob = (r == 1 || r == 3) ? (1.0f - p) : p;
            if (r >= 4) prob = 0.5f;
            prob = fminf(fmaxf(prob, EPS_P), 1.0f - EPS_P);
            loss += t ? -logf(prob) : -log1pf(-prob);
            valid += 1.0f;
        }
    }

    // wave-64 reduce
    #pragma unroll
    for (int off = 32; off > 0; off >>= 1) {
        loss  += __shfl_down(loss, off, 64);
        valid += __shfl_down(valid, off, 64);
    }

    __shared__ float s_l[4];
    __shared__ float s_v[4];
    const int lane = threadIdx.x & 63;
    const int wave = threadIdx.x >> 6;
    if (lane == 0) { s_l[wave] = loss; s_v[wave] = valid; }
    __syncthreads();
    if (threadIdx.x == 0) {
        part_sum[blockIdx.x] = s_l[0] + s_l[1] + s_l[2] + s_l[3];
        part_cnt[blockIdx.x] = s_v[0] + s_v[1] + s_v[2] + s_v[3];
    }
}

__global__ __launch_bounds__(256)
void claim_loss_final(const float* __restrict__ part_sum,
                      const float* __restrict__ part_cnt,
                      float* __restrict__ out) {
    float s = part_sum[threadIdx.x];
    float c = part_cnt[threadIdx.x];

    #pragma unroll
    for (int off = 32; off > 0; off >>= 1) {
        s += __shfl_down(s, off, 64);
        c += __shfl_down(c, off, 64);
    }

    __shared__ float s_l[4];
    __shared__ float s_v[4];
    const int lane = threadIdx.x & 63;
    const int wave = threadIdx.x >> 6;
    if (lane == 0) { s_l[wave] = s; s_v[wave] = c; }
    __syncthreads();

    if (threadIdx.x == 0) {
        float S = s_l[0] + s_l[1] + s_l[2] + s_l[3];
        float C = s_v[0] + s_v[1] + s_v[2] + s_v[3];
        out[0] = (C > 0.0f) ? (S / fmaxf(C, 1.0f)) : 0.0f;
    }
}

extern "C" void kernel_launch(void* const* d_in, const int* in_sizes, int n_in,
                              void* d_out, int out_size, void* d_ws, size_t ws_size,
                              hipStream_t stream) {
    const float* adj     = (const float*)d_in[0];
    const int*   var_a   = (const int*)d_in[1];
    const int*   var_b   = (const int*)d_in[2];
    const int*   rel     = (const int*)d_in[3];
    const int*   is_true = (const int*)d_in[4];
    const unsigned int* mask = (const unsigned int*)d_in[5];

    float* part_sum = (float*)d_ws;
    float* part_cnt = (float*)d_ws + NBLK;
    float* out      = (float*)d_out;

    claim_loss_main<<<NBLK, 256, 0, stream>>>(
        adj, var_a, var_b, rel, is_true, mask, part_sum, part_cnt);
    claim_loss_final<<<1, 256, 0, stream>>>(part_sum, part_cnt, out);
}